// Round 4
// baseline (96.310 us; speedup 1.0000x reference)
//
#include <hip/hip_runtime.h>
#include <cstdint>

#define NV 200000
#define NCOLS 5
#define P 128
#define NE 8192
#define NC 1024

typedef float v2f __attribute__((ext_vector_type(2)));

// Kernel 1: gather all clusters' coords once into dense float4 array.
__global__ __launch_bounds__(256) void gather_kernel(
    const float* __restrict__ data,
    const int*   __restrict__ clusts,
    float4*      __restrict__ ws)
{
    const int idx = blockIdx.x * 256 + threadIdx.x;   // 0 .. NC*P-1
    const int v = clusts[idx];
    ws[idx] = make_float4(data[v * NCOLS + 1], data[v * NCOLS + 2],
                          data[v * NCOLS + 3], 0.f);
}

template <bool USE_WS>
__global__ __launch_bounds__(256) void clust_geo_edge_kernel(
    const float*  __restrict__ data,
    const int*    __restrict__ clusts,
    const int*    __restrict__ edge_index,
    const float4* __restrict__ ws,
    float*        __restrict__ out)
{
    #pragma clang fp contract(off)   // reference does separate mul/add rounding

    const int e = blockIdx.x;
    const int t = threadIdx.x;

    // SoA LDS: rows 0..2 = x1 {x,y,z}, rows 3..5 = x2 {x,y,z}.
    __shared__ float xs[6][P];
    __shared__ unsigned long long wmin[4];

    const int c1 = edge_index[e];
    const int c2 = edge_index[NE + e];

    if (USE_WS) {
        if (t < P) {
            const float4 p4 = ws[c1 * P + t];
            xs[0][t] = p4.x; xs[1][t] = p4.y; xs[2][t] = p4.z;
        } else {
            const int p = t - P;
            const float4 p4 = ws[c2 * P + p];
            xs[3][p] = p4.x; xs[4][p] = p4.y; xs[5][p] = p4.z;
        }
    } else {
        if (t < P) {
            const int v = clusts[c1 * P + t];
            xs[0][t] = data[v * NCOLS + 1];
            xs[1][t] = data[v * NCOLS + 2];
            xs[2][t] = data[v * NCOLS + 3];
        } else {
            const int p = t - P;
            const int v = clusts[c2 * P + p];
            xs[3][p] = data[v * NCOLS + 1];
            xs[4][p] = data[v * NCOLS + 2];
            xs[5][p] = data[v * NCOLS + 3];
        }
    }
    __syncthreads();

    // Thread (ti,tj): i in {2ti + 32q + h : q=0..3, h=0..1} (adjacent pairs,
    // one ds_read_b64 each), j in {tj + 16m : m=0..7}.
    const int tj = t & 15;
    const int ti = t >> 4;

    v2f ax2[4], ay2[4], az2[4];
    #pragma unroll
    for (int q = 0; q < 4; ++q) {
        const int i = 2 * ti + 32 * q;
        ax2[q] = *(const v2f*)&xs[0][i];
        ay2[q] = *(const v2f*)&xs[1][i];
        az2[q] = *(const v2f*)&xs[2][i];
    }
    float bx[8], by[8], bz[8];
    #pragma unroll
    for (int m = 0; m < 8; ++m) {
        const int j = tj + 16 * m;
        bx[m] = xs[3][j]; by[m] = xs[4][j]; bz[m] = xs[5][j];
    }

    // Per-i running best over j (strict < with m ascending keeps smallest j).
    float bd[4][2];
    int   bm[4][2];
    #pragma unroll
    for (int q = 0; q < 4; ++q) {
        bd[q][0] = __builtin_inff(); bd[q][1] = __builtin_inff();
        bm[q][0] = 0;                bm[q][1] = 0;
    }

    // Exact reference fp32 arithmetic ((dx*dx + dy*dy) + dz*dz, unfused),
    // packed 2 i's per v_pk op.
    #pragma unroll
    for (int m = 0; m < 8; ++m) {
        const v2f bxx = { bx[m], bx[m] };
        const v2f byy = { by[m], by[m] };
        const v2f bzz = { bz[m], bz[m] };
        #pragma unroll
        for (int q = 0; q < 4; ++q) {
            const v2f dx = ax2[q] - bxx;
            const v2f dy = ay2[q] - byy;
            const v2f dz = az2[q] - bzz;
            const v2f d2 = (dx * dx + dy * dy) + dz * dz;
            if (d2.x < bd[q][0]) { bd[q][0] = d2.x; bm[q][0] = m; }
            if (d2.y < bd[q][1]) { bd[q][1] = d2.y; bm[q][1] = m; }
        }
    }

    // Combine per-i bests with i ascending: ties keep smaller i => smaller flat.
    float bestd = __builtin_inff();
    int   bestflat = 0;
    #pragma unroll
    for (int q = 0; q < 4; ++q) {
        #pragma unroll
        for (int h = 0; h < 2; ++h) {
            const int i = 2 * ti + 32 * q + h;
            const int flat = i * P + (tj + 16 * bm[q][h]);
            if (bd[q][h] < bestd) { bestd = bd[q][h]; bestflat = flat; }
        }
    }

    // Pack (d2, flat): d2 >= 0 so float bits are monotone as uint.
    // min(key) == (min d2, then min flat) — matches jnp.argmin tie-break.
    unsigned long long key =
        ((unsigned long long)__float_as_uint(bestd) << 32) | (unsigned)bestflat;

    for (int off = 32; off > 0; off >>= 1) {
        unsigned long long other = __shfl_down(key, off, 64);
        if (other < key) key = other;
    }
    const int wave = t >> 6;
    if ((t & 63) == 0) wmin[wave] = key;
    __syncthreads();

    if (t == 0) {
        unsigned long long k0 = wmin[0];
        #pragma unroll
        for (int w = 1; w < 4; ++w) if (wmin[w] < k0) k0 = wmin[w];
        const int flat = (int)(k0 & 0xffffffffull);
        const int i1 = flat >> 7;
        const int i2 = flat & (P - 1);

        const float v1x = xs[0][i1], v1y = xs[1][i1], v1z = xs[2][i1];
        const float v2x = xs[3][i2], v2y = xs[4][i2], v2z = xs[5][i2];

        const float dx = v1x - v2x, dy = v1y - v2y, dz = v1z - v2z;
        const float lend = sqrtf(dx * dx + dy * dy + dz * dz);

        float nx, ny, nz;
        if (lend > 0.f) { nx = dx / lend; ny = dy / lend; nz = dz / lend; }
        else            { nx = dx;        ny = dy;        nz = dz;        }

        const float B[9] = { nx*nx, nx*ny, nx*nz,
                             ny*nx, ny*ny, ny*nz,
                             nz*nx, nz*ny, nz*nz };

        float* o = out + (size_t)e * 38;
        o[0] = v1x; o[1] = v1y; o[2] = v1z;
        o[3] = v2x; o[4] = v2y; o[5] = v2z;
        o[6] = nx;  o[7] = ny;  o[8] = nz;  o[9] = lend;
        #pragma unroll
        for (int q = 0; q < 9; ++q) o[10 + q] = B[q];
        o[19] = v2x; o[20] = v2y; o[21] = v2z;
        o[22] = v1x; o[23] = v1y; o[24] = v1z;
        o[25] = -nx; o[26] = -ny; o[27] = -nz; o[28] = lend;
        #pragma unroll
        for (int q = 0; q < 9; ++q) o[29 + q] = B[q];
    }
}

extern "C" void kernel_launch(void* const* d_in, const int* in_sizes, int n_in,
                              void* d_out, int out_size, void* d_ws, size_t ws_size,
                              hipStream_t stream) {
    const float* data       = (const float*)d_in[0];
    const int*   clusts     = (const int*)d_in[1];
    const int*   edge_index = (const int*)d_in[2];
    float*       out        = (float*)d_out;
    float4*      ws         = (float4*)d_ws;

    const size_t need = (size_t)NC * P * sizeof(float4);  // 2 MB
    if (ws_size >= need) {
        gather_kernel<<<(NC * P) / 256, 256, 0, stream>>>(data, clusts, ws);
        clust_geo_edge_kernel<true><<<NE, 256, 0, stream>>>(data, clusts, edge_index, ws, out);
    } else {
        clust_geo_edge_kernel<false><<<NE, 256, 0, stream>>>(data, clusts, edge_index, ws, out);
    }
}